// Round 12
// baseline (443.912 us; speedup 1.0000x reference)
//
#include <hip/hip_runtime.h>
#include <hip/hip_bf16.h>

#define D_DIM 512
#define H_DIM 512
#define G_SEG 1024
#define BM    64
#define TILES 16

typedef __attribute__((ext_vector_type(8))) short bf16x8;
typedef __attribute__((ext_vector_type(4))) float f32x4;
typedef unsigned int u32;
typedef unsigned short u16;

// ---- workspace ----
#define WS_S    0                 // G f32
#define WS_WB   8192              // 512 KB bf16 W granule layout
#define WS_E16  (1u << 20)        // 256 MB bf16 E in 64KB tile-image layout

// ---- LDS: two 64KB tile buffers + misc ----
#define BUF0_OFF  0
#define BUF1_OFF  (BM * 1024)
#define BETA_OFF  (2 * BM * 1024)
#define EBS_OFF   (BETA_OFF + 4 * BM * 4)
#define SIDX_OFF  (EBS_OFF + BM * 4)
#define SCR_OFF   (SIDX_OFF + BM * 4)
#define LDS_TOTAL (SCR_OFF + 4 * 512 * 4)   // 140800 B -> 1 block/CU

#define GLOBAL_AS __attribute__((address_space(1)))
#define LDS_AS    __attribute__((address_space(3)))

static __device__ __forceinline__ void gload_lds16(const void* g, void* l) {
    __builtin_amdgcn_global_load_lds((const GLOBAL_AS u32*)g, (LDS_AS u32*)l, 16, 0, 0);
}
static __device__ __forceinline__ u16 f2bf(float f) {
    __hip_bfloat16 h = __float2bfloat16(f);
    return *(u16*)&h;
}
static __device__ __forceinline__ float bf2f(u16 u) {
    return __uint_as_float(((u32)u) << 16);
}
static __device__ __forceinline__ float fast_tanh(float x) {
    float e = exp2f(x * 2.885390081777927f);   // e^(2x)
    return 1.0f - 2.0f * __builtin_amdgcn_rcpf(e + 1.0f);
}
static __device__ __forceinline__ void pack8(const float4& a, const float4& b, void* dst) {
    u16 h[8];
    h[0]=f2bf(a.x); h[1]=f2bf(a.y); h[2]=f2bf(a.z); h[3]=f2bf(a.w);
    h[4]=f2bf(b.x); h[5]=f2bf(b.y); h[6]=f2bf(b.z); h[7]=f2bf(b.w);
    *(uint4*)dst = *(uint4*)h;
}
// raw barrier, LDS ordering only — never drains vmcnt (keeps async loads in flight)
static __device__ __forceinline__ void barrier_lds() {
    asm volatile("s_waitcnt lgkmcnt(0)" ::: "memory");
    __builtin_amdgcn_s_barrier();
    __builtin_amdgcn_sched_barrier(0);
}

// ---- W fp32 -> bf16 granule layout ----
__global__ __launch_bounds__(256)
void cvt_w(const float* __restrict__ W, u16* __restrict__ Wb) {
    int t   = blockIdx.x * 256 + threadIdx.x;
    int lhi = t & 3;
    int c   = (t >> 2) & 511;
    int k32 = t >> 11;
    const float* src = W + (size_t)c * 512 + k32 * 32 + lhi * 8;
    pack8(*(const float4*)src, *(const float4*)(src + 4), Wb + (size_t)t * 8);
}

// ---- E fp32 -> bf16 tile-image layout (64-row tiles, XOR swizzle baked in) ----
// chunk c (16B of E16): rowg = c>>6, j = c&63; tile tau = rowg>>6, r = rowg&63
// byte offset = tau*65536 + r*1024 + ((j*16) ^ ((r&7)<<4))
__global__ __launch_bounds__(256)
void cvt_e(const float* __restrict__ E, u16* __restrict__ E16, int nChunks) {
    const int stride = gridDim.x * 256;
#pragma unroll 1
    for (int c = blockIdx.x * 256 + threadIdx.x; c < nChunks; c += stride) {
        int rowg = c >> 6, j = c & 63;
        const float* src = E + (size_t)rowg * 512 + j * 8;
        float4 f0 = *(const float4*)src;
        float4 f1 = *(const float4*)(src + 4);
        int tau = rowg >> 6, r = rowg & 63;
        size_t off = ((size_t)tau << 16) + r * 1024 + ((j << 4) ^ ((r & 7) << 4));
        pack8(f0, f1, (char*)E16 + off);
    }
}

// ---- fused: per 64-row tile: GEMM + tanh*V + exp + segment sums ----
// A via async gload_lds double-buffer (next tile in flight during current compute).
__global__ __launch_bounds__(256, 1)
void fused(const u16* __restrict__ E16, const int* __restrict__ BI,
           const u16* __restrict__ Wb, const float* __restrict__ V,
           float* __restrict__ out, float* __restrict__ S)
{
    extern __shared__ char smem[];
    const int tid = threadIdx.x;
    const int l   = tid & 63;
    const int w   = tid >> 6;     // col group: cols [w*128, +128)
    const int l15 = l & 15;
    const int lhi = l >> 4;
    const int tile0 = blockIdx.x * TILES;

    const int bOffBase = ((w * 128 + l15) * 4 + lhi) * 16;
    const char* Wbb = (const char*)Wb;

    float Vv[8];
#pragma unroll
    for (int n = 0; n < 8; ++n)
        Vv[n] = V[w * 128 + n * 16 + l15];

    // issue one tile's 16 async loads (wave w covers its 16KB quarter)
    auto issueTile = [&](int gTile, char* buf) {
        const char* src = (const char*)E16 + ((size_t)gTile << 16)
                        + (size_t)w * 16384 + (size_t)l * 16;
        char* dst = buf + w * 16384;
#pragma unroll
        for (int i = 0; i < 16; ++i)
            gload_lds16(src + i * 1024, dst + i * 1024);
    };

    // prologue: tile0 -> buf0
    issueTile(tile0, smem + BUF0_OFF);

    bf16x8 bA[8], bB[8];
#pragma unroll
    for (int n = 0; n < 8; ++n)
        bA[n] = *(const bf16x8*)(Wbb + bOffBase + n * 1024);

    int cur = 0;
#pragma unroll 1
    for (int t = 0; t < TILES; ++t) {
        char* bufC = smem + (cur ? BUF1_OFF : BUF0_OFF);
        char* bufN = smem + (cur ? BUF0_OFF : BUF1_OFF);
        const bool more = (t + 1 < TILES);
        const int  nodeBase = (tile0 + t) * BM;

        // issue next tile, then wait ONLY for current tile's 16 loads (counted vmcnt)
        if (more) {
            issueTile(tile0 + t + 1, bufN);
            asm volatile("s_waitcnt vmcnt(16)" ::: "memory");
        } else {
            asm volatile("s_waitcnt vmcnt(0)" ::: "memory");
        }
        __builtin_amdgcn_sched_barrier(0);
        __builtin_amdgcn_s_barrier();
        __builtin_amdgcn_sched_barrier(0);

        f32x4 acc[4][8];
#pragma unroll
        for (int m = 0; m < 4; ++m)
#pragma unroll
            for (int n = 0; n < 8; ++n) acc[m][n] = (f32x4){0.f, 0.f, 0.f, 0.f};

        // ---- K-loop: 8 kk2 pairs, b reg-dbuf from L2-resident Wb ----
#pragma unroll 1
        for (int kk2 = 0; kk2 < 8; ++kk2) {
            {   // half A: compute kk=2*kk2 with bA; prefetch bB
                const char* Wn = Wbb + ((size_t)(2 * kk2 + 1) << 15);
#pragma unroll
                for (int n = 0; n < 8; ++n)
                    bB[n] = *(const bf16x8*)(Wn + bOffBase + n * 1024);
                bf16x8 a[4];
                const int kbyte = (2 * kk2) * 64 + lhi * 16;
#pragma unroll
                for (int m = 0; m < 4; ++m) {
                    int row = m * 16 + l15;
                    a[m] = *(const bf16x8*)(bufC + row * 1024 + (kbyte ^ ((row & 7) << 4)));
                }
#pragma unroll
                for (int m = 0; m < 4; ++m)
#pragma unroll
                    for (int n = 0; n < 8; ++n)
                        acc[m][n] = __builtin_amdgcn_mfma_f32_16x16x32_bf16(a[m], bA[n], acc[m][n], 0, 0, 0);
            }
            {   // half B: compute kk=2*kk2+1 with bB; prefetch bA
                if (kk2 < 7) {
                    const char* Wn = Wbb + ((size_t)(2 * kk2 + 2) << 15);
#pragma unroll
                    for (int n = 0; n < 8; ++n)
                        bA[n] = *(const bf16x8*)(Wn + bOffBase + n * 1024);
                }
                bf16x8 a[4];
                const int kbyte = (2 * kk2 + 1) * 64 + lhi * 16;
#pragma unroll
                for (int m = 0; m < 4; ++m) {
                    int row = m * 16 + l15;
                    a[m] = *(const bf16x8*)(bufC + row * 1024 + (kbyte ^ ((row & 7) << 4)));
                }
#pragma unroll
                for (int m = 0; m < 4; ++m)
#pragma unroll
                    for (int n = 0; n < 8; ++n)
                        acc[m][n] = __builtin_amdgcn_mfma_f32_16x16x32_bf16(a[m], bB[n], acc[m][n], 0, 0, 0);
            }
        }

        if (more) {   // preload bA for next tile's first slab during epilogue
#pragma unroll
            for (int n = 0; n < 8; ++n)
                bA[n] = *(const bf16x8*)(Wbb + bOffBase + n * 1024);
        }

        // ---- epilogue: beta-partial over this wave's 128 cols ----
        float bsum[4][4];
#pragma unroll
        for (int m = 0; m < 4; ++m)
#pragma unroll
            for (int r = 0; r < 4; ++r) {
                float s = 0.f;
#pragma unroll
                for (int n = 0; n < 8; ++n)
                    s += Vv[n] * fast_tanh(acc[m][n][r]);
                bsum[m][r] = s;
            }
#pragma unroll
        for (int off = 1; off <= 8; off <<= 1)
#pragma unroll
            for (int m = 0; m < 4; ++m)
#pragma unroll
                for (int r = 0; r < 4; ++r)
                    bsum[m][r] += __shfl_xor(bsum[m][r], off, 64);

        float* betaP = (float*)(smem + BETA_OFF);
        if (l15 == 0) {
#pragma unroll
            for (int m = 0; m < 4; ++m)
#pragma unroll
                for (int r = 0; r < 4; ++r)
                    betaP[w * BM + m * 16 + lhi * 4 + r] = bsum[m][r];
        }
        barrier_lds();

        // ---- eb = exp(beta); S[g] += eb (wave 0; rows sorted) ----
        float* ebs  = (float*)(smem + EBS_OFF);
        int*   sidx = (int*)(smem + SIDX_OFF);
        if (tid < BM) {
            float beta = betaP[tid] + betaP[BM + tid] + betaP[2 * BM + tid] + betaP[3 * BM + tid];
            float eb = expf(beta);
            ebs[tid] = eb;
            int g = BI[nodeBase + tid];
            sidx[tid] = g;
            int g0 = __shfl(g, 0, 64);
            if (__all(g == g0)) {
                float s = eb;
#pragma unroll
                for (int off = 1; off <= 32; off <<= 1)
                    s += __shfl_xor(s, off, 64);
                if (l == 0) atomicAdd(&S[g], s);
            } else {
                atomicAdd(&S[g], eb);
            }
        }
        barrier_lds();

        // ---- weighted segment sum: wave w rows [16w,+16); lane l cols [8l,+8).
        // Flush transposes through per-wave LDS scratch -> lane-contiguous atomics.
        {
            float* scr = (float*)(smem + SCR_OFF) + w * 512;
            const int rbase = w * 16;
            float a8[8];
#pragma unroll
            for (int j = 0; j < 8; ++j) a8[j] = 0.f;
            int gcur = sidx[rbase];

#pragma unroll 1
            for (int rr = 0; rr < 16; ++rr) {
                int r = rbase + rr;
                int g = sidx[r];                     // wave-uniform
                if (g != gcur) {
                    *(float4*)(scr + l * 8)     = make_float4(a8[0], a8[1], a8[2], a8[3]);
                    *(float4*)(scr + l * 8 + 4) = make_float4(a8[4], a8[5], a8[6], a8[7]);
                    asm volatile("s_waitcnt lgkmcnt(0)" ::: "memory");
#pragma unroll
                    for (int j = 0; j < 8; ++j)
                        atomicAdd(&out[(size_t)gcur * 512 + j * 64 + l], scr[j * 64 + l]);
#pragma unroll
                    for (int j = 0; j < 8; ++j) a8[j] = 0.f;
                    gcur = g;
                }
                float wgt = ebs[r];
                bf16x8 v = *(const bf16x8*)(bufC + r * 1024 + ((l * 16) ^ ((r & 7) << 4)));
#pragma unroll
                for (int j = 0; j < 8; ++j)
                    a8[j] += wgt * bf2f((u16)v[j]);
            }
            *(float4*)(scr + l * 8)     = make_float4(a8[0], a8[1], a8[2], a8[3]);
            *(float4*)(scr + l * 8 + 4) = make_float4(a8[4], a8[5], a8[6], a8[7]);
            asm volatile("s_waitcnt lgkmcnt(0)" ::: "memory");
#pragma unroll
            for (int j = 0; j < 8; ++j)
                atomicAdd(&out[(size_t)gcur * 512 + j * 64 + l], scr[j * 64 + l]);
        }

        // protect bufC: next iteration's gload_lds writes it
        __builtin_amdgcn_s_barrier();
        __builtin_amdgcn_sched_barrier(0);
        cur ^= 1;
    }
}

__global__ __launch_bounds__(256)
void finalize_kernel(float* __restrict__ out, const float* __restrict__ S) {
    int idx = blockIdx.x * 256 + threadIdx.x;
    float s = S[idx >> 9];
    float v = out[idx];
    out[idx] = (s != 0.f) ? v * __builtin_amdgcn_rcpf(s) : 0.f;
}

extern "C" void kernel_launch(void* const* d_in, const int* in_sizes, int n_in,
                              void* d_out, int out_size, void* d_ws, size_t ws_size,
                              hipStream_t stream) {
    const float* E  = (const float*)d_in[0];
    const int*   BI = (const int*)d_in[1];
    const float* W  = (const float*)d_in[2];
    const float* V  = (const float*)d_in[3];
    float* out = (float*)d_out;
    char*  ws  = (char*)d_ws;
    const int Ntot = in_sizes[0] / D_DIM;

    float* S   = (float*)(ws + WS_S);
    u16*   Wb  = (u16*)(ws + WS_WB);
    u16*   E16 = (u16*)(ws + WS_E16);

    hipMemsetAsync(S, 0, G_SEG * 4, stream);
    hipMemsetAsync(out, 0, (size_t)out_size * 4, stream);
    hipFuncSetAttribute((const void*)fused,
                        hipFuncAttributeMaxDynamicSharedMemorySize, LDS_TOTAL);

    cvt_w<<<128, 256, 0, stream>>>(W, Wb);
    cvt_e<<<2048, 256, 0, stream>>>(E, E16, Ntot * 64);
    fused<<<Ntot / (BM * TILES), 256, LDS_TOTAL, stream>>>(E16, BI, Wb, V, out, S);
    finalize_kernel<<<out_size / 256, 256, 0, stream>>>(out, S);
}